// Round 1
// baseline (296.046 us; speedup 1.0000x reference)
//
#include <hip/hip_runtime.h>
#include <math.h>

#define BB 16
#define CINC 3
#define COUTC 64
#define HH 256
#define WWD 256
#define NBLK (BB*HH)          // 4096 blocks for kernel1
#define NPIX (BB*HH*WWD)      // 1,048,576 pixels

// ---------------------------------------------------------------------------
// Kernel 1: offset conv + deformable sampling + DCN matmul + residual conv.
// One block per (b,h) row; thread = w. Writes y to out, per-block per-channel
// sum/sumsq partials to psum/psq (deterministic reduction order).
// ---------------------------------------------------------------------------
__global__ __launch_bounds__(256) void dcn_fused_kernel(
    const float* __restrict__ x,
    const float* __restrict__ w_off,
    const float* __restrict__ b_off,
    const float* __restrict__ w_dcn,
    const float* __restrict__ w_conv,
    const float* __restrict__ b_conv,
    float* __restrict__ out,
    float* __restrict__ psum,     // [64][NBLK]
    float* __restrict__ psq)      // [64][NBLK]
{
    const int tid = threadIdx.x;
    const int b = blockIdx.x >> 8;
    const int h = blockIdx.x & 255;
    const int w = tid;

    __shared__ float ybuf[16][257];   // +1 pad: conflict-free transpose reduce
    __shared__ float lds2s[4][16];
    __shared__ float lds2q[4][16];

    const float* xb = x + (size_t)b * (CINC*HH*WWD);

    // --- 3x3 zero-padded neighborhood, 3 channels -------------------------
    float xn[3][3][3];
    #pragma unroll
    for (int c = 0; c < 3; ++c) {
        #pragma unroll
        for (int dy = 0; dy < 3; ++dy) {
            int yy = h + dy - 1;
            #pragma unroll
            for (int dx = 0; dx < 3; ++dx) {
                int xx = w + dx - 1;
                bool ok = (yy >= 0) && (yy < HH) && (xx >= 0) && (xx < WWD);
                xn[c][dy][dx] = ok ? xb[c*(HH*WWD) + yy*WWD + xx] : 0.f;
            }
        }
    }

    // --- offset conv: 18 channels (weights are wave-uniform -> s_load) ----
    float off[18];
    #pragma unroll
    for (int j = 0; j < 18; ++j) off[j] = b_off[j];
    #pragma unroll
    for (int c = 0; c < 3; ++c)
        #pragma unroll
        for (int ky = 0; ky < 3; ++ky)
            #pragma unroll
            for (int kx = 0; kx < 3; ++kx) {
                float v = xn[c][ky][kx];
                #pragma unroll
                for (int j = 0; j < 18; ++j)
                    off[j] = fmaf(v, w_off[((j*3 + c)*3 + ky)*3 + kx], off[j]);
            }

    // --- deformable bilinear taps: taps[k][c] -----------------------------
    float taps[9][3];
    #pragma unroll
    for (int k = 0; k < 9; ++k) {
        const int ky = k / 3, kx = k % 3;
        float py = (float)(h + ky - 1) + off[2*k];
        float px = (float)(w + kx - 1) + off[2*k + 1];
        float y0f = floorf(py), x0f = floorf(px);
        float ly = py - y0f, lx = px - x0f;
        float hy = 1.f - ly, hx = 1.f - lx;
        int y0 = (int)y0f, x0 = (int)x0f;
        int y1 = y0 + 1,  x1 = x0 + 1;
        bool vy0 = (y0 >= 0) && (y0 < HH);
        bool vy1 = (y1 >= 0) && (y1 < HH);
        bool vx0 = (x0 >= 0) && (x0 < WWD);
        bool vx1 = (x1 >= 0) && (x1 < WWD);
        float w00 = (vy0 && vx0) ? hy*hx : 0.f;
        float w01 = (vy0 && vx1) ? hy*lx : 0.f;
        float w10 = (vy1 && vx0) ? ly*hx : 0.f;
        float w11 = (vy1 && vx1) ? ly*lx : 0.f;
        int yc0 = min(max(y0, 0), HH-1),  yc1 = min(max(y1, 0), HH-1);
        int xc0 = min(max(x0, 0), WWD-1), xc1 = min(max(x1, 0), WWD-1);
        int i00 = yc0*WWD + xc0, i01 = yc0*WWD + xc1;
        int i10 = yc1*WWD + xc0, i11 = yc1*WWD + xc1;
        #pragma unroll
        for (int c = 0; c < 3; ++c) {
            const float* xc = xb + c*(HH*WWD);
            taps[k][c] = w00*xc[i00] + w01*xc[i01] + w10*xc[i10] + w11*xc[i11];
        }
    }

    // --- 64-channel fused DCN + residual conv, 16-channel chunks ----------
    float* outb = out + (size_t)b * (COUTC*HH*WWD) + h*WWD + w;
    #pragma unroll 1
    for (int q = 0; q < 4; ++q) {
        #pragma unroll
        for (int i = 0; i < 16; ++i) {
            const int o = q*16 + i;
            float acc = b_conv[o];
            #pragma unroll
            for (int c = 0; c < 3; ++c)
                #pragma unroll
                for (int k = 0; k < 9; ++k)
                    acc = fmaf(taps[k][c], w_dcn[o*27 + c*9 + k], acc);
            #pragma unroll
            for (int c = 0; c < 3; ++c)
                #pragma unroll
                for (int ky = 0; ky < 3; ++ky)
                    #pragma unroll
                    for (int kx = 0; kx < 3; ++kx)
                        acc = fmaf(xn[c][ky][kx], w_conv[o*27 + c*9 + ky*3 + kx], acc);
            ybuf[i][w] = acc;
            outb[(size_t)o * (HH*WWD)] = acc;
        }
        __syncthreads();
        // transpose reduce: thread t -> channel t&15, 16-pixel segment t>>4
        {
            const int ch = tid & 15, seg = tid >> 4;
            float s = 0.f, s2 = 0.f;
            #pragma unroll
            for (int i = 0; i < 16; ++i) {
                float v = ybuf[ch][seg*16 + i];
                s += v;
                s2 = fmaf(v, v, s2);
            }
            // combine the 4 segments resident in this wave (deterministic)
            s  += __shfl_xor(s, 16);  s  += __shfl_xor(s, 32);
            s2 += __shfl_xor(s2, 16); s2 += __shfl_xor(s2, 32);
            const int lane = tid & 63, wv = tid >> 6;
            if (lane < 16) { lds2s[wv][lane] = s; lds2q[wv][lane] = s2; }
        }
        __syncthreads();
        if (tid < 16) {
            float s  = lds2s[0][tid] + lds2s[1][tid] + lds2s[2][tid] + lds2s[3][tid];
            float s2 = lds2q[0][tid] + lds2q[1][tid] + lds2q[2][tid] + lds2q[3][tid];
            psum[(q*16 + tid)*NBLK + blockIdx.x] = s;
            psq [(q*16 + tid)*NBLK + blockIdx.x] = s2;
        }
        __syncthreads();
    }
}

// ---------------------------------------------------------------------------
// Kernel 2: reduce partials -> per-channel scale/shift (deterministic order)
// ---------------------------------------------------------------------------
__global__ __launch_bounds__(256) void bn_stats_kernel(
    const float* __restrict__ psum,
    const float* __restrict__ psq,
    const float* __restrict__ gamma,
    const float* __restrict__ beta,
    float* __restrict__ ss)       // [0..63]=scale, [64..127]=shift
{
    __shared__ float rs[256], rq[256];
    const int ch = blockIdx.x, tid = threadIdx.x;
    float s = 0.f, s2 = 0.f;
    for (int j = tid; j < NBLK; j += 256) {
        s  += psum[ch*NBLK + j];
        s2 += psq [ch*NBLK + j];
    }
    rs[tid] = s; rq[tid] = s2;
    __syncthreads();
    for (int st = 128; st > 0; st >>= 1) {
        if (tid < st) { rs[tid] += rs[tid + st]; rq[tid] += rq[tid + st]; }
        __syncthreads();
    }
    if (tid == 0) {
        const float N = (float)NPIX;
        float mean = rs[0] / N;
        float var  = rq[0] / N - mean*mean;
        float rstd = rsqrtf(var + 1e-5f);
        float sc   = gamma[ch] * rstd;
        ss[ch]      = sc;
        ss[64 + ch] = beta[ch] - mean * sc;
    }
}

// ---------------------------------------------------------------------------
// Kernel 3: in-place affine + SiLU over d_out (float4, memory-bound)
// ---------------------------------------------------------------------------
__global__ __launch_bounds__(256) void bn_silu_kernel(
    float* __restrict__ y,
    const float* __restrict__ ss)
{
    __shared__ float sc[64], sh[64];
    if (threadIdx.x < 64) {
        sc[threadIdx.x] = ss[threadIdx.x];
        sh[threadIdx.x] = ss[64 + threadIdx.x];
    }
    __syncthreads();
    float4* y4 = (float4*)y;
    const int total4 = (BB*COUTC*HH*WWD) / 4;   // 16,777,216
    for (int i = blockIdx.x*256 + threadIdx.x; i < total4; i += gridDim.x*256) {
        float4 v = y4[i];
        const int o = (i >> 14) & 63;           // element_idx>>16 & 63
        const float a = sc[o], t = sh[o];
        float z;
        z = fmaf(v.x, a, t); v.x = z / (1.f + __expf(-z));
        z = fmaf(v.y, a, t); v.y = z / (1.f + __expf(-z));
        z = fmaf(v.z, a, t); v.z = z / (1.f + __expf(-z));
        z = fmaf(v.w, a, t); v.w = z / (1.f + __expf(-z));
        y4[i] = v;
    }
}

// ---------------------------------------------------------------------------
extern "C" void kernel_launch(void* const* d_in, const int* in_sizes, int n_in,
                              void* d_out, int out_size, void* d_ws, size_t ws_size,
                              hipStream_t stream) {
    const float* x      = (const float*)d_in[0];
    const float* w_off  = (const float*)d_in[1];
    const float* b_off  = (const float*)d_in[2];
    const float* w_dcn  = (const float*)d_in[3];
    const float* w_conv = (const float*)d_in[4];
    const float* b_conv = (const float*)d_in[5];
    const float* gamma  = (const float*)d_in[6];
    const float* beta   = (const float*)d_in[7];
    float* out = (float*)d_out;

    float* psum = (float*)d_ws;                    // 64*4096
    float* psq  = psum + 64*NBLK;                  // 64*4096
    float* ss   = psq  + 64*NBLK;                  // 128 floats

    dcn_fused_kernel<<<NBLK, 256, 0, stream>>>(x, w_off, b_off, w_dcn, w_conv,
                                               b_conv, out, psum, psq);
    bn_stats_kernel<<<64, 256, 0, stream>>>(psum, psq, gamma, beta, ss);
    bn_silu_kernel<<<2048, 256, 0, stream>>>(out, ss);
}